// Round 1
// baseline (298.929 us; speedup 1.0000x reference)
//
#include <hip/hip_runtime.h>

#define CH   16
#define HID  128
#define PC   48      // perception channels = 3*CH
#define WD   256
#define HD   256

// Each block: 256 threads, covers 2 full image rows (one rowpair) of one image.
// Each thread: 2 vertically adjacent pixels (y0, y0+1) at column x = tid.
__global__ __launch_bounds__(256, 2) void nca_fused_kernel(
    const float* __restrict__ grid,
    const float* __restrict__ W1, const float* __restrict__ b1,
    const float* __restrict__ W2, const float* __restrict__ b2,
    float* __restrict__ out)
{
    __shared__ float sW1[HID * PC];   // 6144 floats, sobel /8 pre-folded
    __shared__ float sB1[HID];
    __shared__ float sW2t[HID * CH];  // transposed: [o][j]
    __shared__ float sB2[CH];

    const int tid = threadIdx.x;

    // ---- stage weights into LDS ----
    for (int i = tid; i < HID * PC; i += 256) {
        int c = i % PC;
        sW1[i] = W1[i] * (c < CH ? 1.0f : 0.125f);   // fold sobel's /8
    }
    for (int i = tid; i < HID; i += 256) sB1[i] = b1[i];
    for (int i = tid; i < HID * CH; i += 256) {
        int o = i >> 4, j = i & 15;
        sW2t[i] = W2[j * HID + o];
    }
    if (tid < CH) sB2[tid] = b2[tid];
    __syncthreads();

    // ---- block -> (image b, rowpair) ----
    const int blk = blockIdx.x;
    const int b  = blk >> 7;        // 128 rowpairs per image
    const int rp = blk & 127;
    const int y0 = rp * 2;          // pixel0 row; pixel1 row = y0+1
    const int x  = tid;

    // clamped indices + 0/1 masks for zero padding
    const float mxl = (x > 0)      ? 1.0f : 0.0f;
    const float mxr = (x < WD - 1) ? 1.0f : 0.0f;
    const int   xl  = (x > 0)      ? x - 1 : x;
    const int   xr  = (x < WD - 1) ? x + 1 : x;
    const float myt = (y0 > 0)     ? 1.0f : 0.0f;
    const float myb = (y0 + 2 <= HD - 1) ? 1.0f : 0.0f;
    const int   yt  = (y0 > 0)     ? y0 - 1 : y0;
    const int   yb  = (y0 + 2 <= HD - 1) ? y0 + 2 : y0 + 1;

    // ---- build perception for the 2 pixels (48 values each, in VGPRs) ----
    float p0[PC], p1[PC];

    #pragma unroll
    for (int c = 0; c < CH; ++c) {
        const float* base = grid + (size_t)((b * CH + c) * HD) * WD;
        const float* r0 = base + yt * WD;        // row y0-1 (mask myt)
        const float* r1 = base + y0 * WD;        // row y0
        const float* r2 = base + (y0 + 1) * WD;  // row y0+1
        const float* r3 = base + yb * WD;        // row y0+2 (mask myb)

        float a0l = r0[xl] * (mxl * myt), a0c = r0[x] * myt, a0r = r0[xr] * (mxr * myt);
        float a1l = r1[xl] * mxl,         a1c = r1[x],       a1r = r1[xr] * mxr;
        float a2l = r2[xl] * mxl,         a2c = r2[x],       a2r = r2[xr] * mxr;
        float a3l = r3[xl] * (mxl * myb), a3c = r3[x] * myb, a3r = r3[xr] * (mxr * myb);

        p0[c] = a1c;
        p1[c] = a2c;
        // sobel-x (unscaled; /8 folded into sW1): (right - left), row weights 1,2,1
        p0[CH + c] = (a0r - a0l) + 2.0f * (a1r - a1l) + (a2r - a2l);
        p1[CH + c] = (a1r - a1l) + 2.0f * (a2r - a2l) + (a3r - a3l);
        // sobel-y: (bottom - top), col weights 1,2,1
        p0[2 * CH + c] = (a2l - a0l) + 2.0f * (a2c - a0c) + (a2r - a0r);
        p1[2 * CH + c] = (a3l - a1l) + 2.0f * (a3c - a1c) + (a3r - a1r);
    }

    // ---- fused MLP: h = relu(W1 p + b1); acc = W2 h + b2, h never materialized ----
    float acc0[CH], acc1[CH];
    #pragma unroll
    for (int j = 0; j < CH; ++j) { acc0[j] = sB2[j]; acc1[j] = sB2[j]; }

    #pragma unroll 2
    for (int o = 0; o < HID; ++o) {
        float h0 = sB1[o], h1 = h0;
        const float* wr = &sW1[o * PC];
        #pragma unroll
        for (int c = 0; c < PC; ++c) {
            float w = wr[c];            // uniform LDS broadcast
            h0 = fmaf(w, p0[c], h0);
            h1 = fmaf(w, p1[c], h1);
        }
        h0 = fmaxf(h0, 0.0f);
        h1 = fmaxf(h1, 0.0f);
        const float* w2r = &sW2t[o * CH];
        #pragma unroll
        for (int j = 0; j < CH; ++j) {
            float w = w2r[j];
            acc0[j] = fmaf(w, h0, acc0[j]);
            acc1[j] = fmaf(w, h1, acc1[j]);
        }
    }

    // ---- write out: (B, CH, H, W) ----
    float* ob = out + ((size_t)(b * CH) * HD + y0) * WD + x;
    #pragma unroll
    for (int j = 0; j < CH; ++j) {
        ob[(size_t)j * HD * WD]      = acc0[j];
        ob[(size_t)j * HD * WD + WD] = acc1[j];
    }
}

extern "C" void kernel_launch(void* const* d_in, const int* in_sizes, int n_in,
                              void* d_out, int out_size, void* d_ws, size_t ws_size,
                              hipStream_t stream) {
    const float* grid = (const float*)d_in[0];
    const float* W1   = (const float*)d_in[1];
    const float* b1   = (const float*)d_in[2];
    const float* W2   = (const float*)d_in[3];
    const float* b2   = (const float*)d_in[4];
    float* out = (float*)d_out;

    // 16 images * 128 rowpairs = 2048 blocks of 256 threads
    nca_fused_kernel<<<2048, 256, 0, stream>>>(grid, W1, b1, W2, b2, out);
}

// Round 2
// 235.750 us; speedup vs baseline: 1.2680x; 1.2680x over previous
//
#include <hip/hip_runtime.h>

typedef float           f32x16  __attribute__((ext_vector_type(16)));
typedef float           f32x4   __attribute__((ext_vector_type(4)));
typedef __bf16          bf16x8  __attribute__((ext_vector_type(8)));
typedef unsigned short  ushort8 __attribute__((ext_vector_type(8)));

#define MFMA(a,b,c) __builtin_amdgcn_mfma_f32_32x32x16_bf16(a, b, c, 0, 0, 0)

// split fp32 -> bf16 hi + bf16 lo (truncation; lo = exact remainder, then truncated)
__device__ __forceinline__ void bsplit(float x, unsigned short& hi, unsigned short& lo) {
    unsigned u  = __builtin_bit_cast(unsigned, x);
    unsigned hb = u & 0xFFFF0000u;
    hi = (unsigned short)(u >> 16);
    float rem = x - __builtin_bit_cast(float, hb);
    lo = (unsigned short)(__builtin_bit_cast(unsigned, rem) >> 16);
}

// LDS map (byte offsets):
//   W1 frags: [ (og*3+kk)*2+pl ] * 1024 + lane*16          (24 KB)   0..24575
//   W2 frags: 24576 + [ kk2*2+pl ] * 512 + cidx*16         (8 KB)    24576..32767
//   H per wave: 32768 + w*4096, [32 pix][2 pl][32 o] swizzled (16 KB) 32768..49151
__global__ __launch_bounds__(256, 3) void nca_mfma_kernel(
    const float* __restrict__ grid,
    const float* __restrict__ W1, const float* __restrict__ b1,
    const float* __restrict__ W2, const float* __restrict__ b2,
    float* __restrict__ out)
{
    __shared__ unsigned short sLDS[24576];  // 48 KB

    const int tid  = threadIdx.x;
    const int l    = tid & 63;
    const int w    = tid >> 6;
    const int half = l >> 5;
    const int ol   = l & 31;

    // ---------------- stage W1 fragments (pre-split, lane-major) ----------------
    #pragma unroll
    for (int i = 0; i < 3; ++i) {
        int sidx = tid + 256*i;          // 0..767
        int ls   = sidx & 63;
        int fp   = sidx >> 6;            // 0..11 = og*3+kk
        int kk   = fp % 3;
        int o    = (fp/3)*32 + (ls & 31);
        int k0   = kk*16 + (ls>>5)*8;
        float sc = (kk == 0) ? 1.0f : 0.125f;   // fold sobel /8 into W1 (k>=16)
        ushort8 hi8, lo8;
        #pragma unroll
        for (int j = 0; j < 8; ++j) {
            float v = W1[o*48 + k0 + j] * sc;
            unsigned short h, lo_;
            bsplit(v, h, lo_);
            hi8[j] = h; lo8[j] = lo_;
        }
        *(ushort8*)&sLDS[(fp*2 + 0)*512 + ls*8] = hi8;
        *(ushort8*)&sLDS[(fp*2 + 1)*512 + ls*8] = lo8;
    }

    // ---------------- stage W2 fragments (compressed: 32 valid lane-slices) ----------------
    {
        int kk2  = tid >> 5;             // 0..7
        int cidx = tid & 31;             // (l&15) + 16*(l>>5) compressed index
        int o    = cidx & 15;
        int hs   = cidx >> 4;
        int k0   = kk2*16 + hs*8;
        ushort8 hi8, lo8;
        #pragma unroll
        for (int j = 0; j < 8; ++j) {
            float v = W2[o*128 + k0 + j];
            unsigned short h, lo_;
            bsplit(v, h, lo_);
            hi8[j] = h; lo8[j] = lo_;
        }
        *(ushort8*)&sLDS[12288 + (kk2*2 + 0)*256 + cidx*8] = hi8;
        *(ushort8*)&sLDS[12288 + (kk2*2 + 1)*256 + cidx*8] = lo8;
    }

    // per-lane bias values
    const float b1v[4] = { b1[ol], b1[32+ol], b1[64+ol], b1[96+ol] };
    const bool  v16 = (ol < 16);
    const float b2v = v16 ? b2[ol & 15] : 0.0f;

    __syncthreads();

    // ---------------- precomputed LDS addresses ----------------
    const int hbase = 32768 + w*4096;
    const int h4    = half*4;
    const int cb    = (ol >> 3) ^ h4;                 // chunk base for H writes
    int waddrH[4], waddrL[4];
    #pragma unroll
    for (int q = 0; q < 4; ++q) {
        // pix = q + 8*(r>>2) + 4*half ; chunk' = (ol>>3) ^ (q^h4) ; +(r>>2)*1024 as imm
        waddrH[q] = hbase + half*512 + q*128 + ((cb ^ q) << 4) + ((ol & 7) << 1);
        waddrL[q] = waddrH[q] ^ 64;                   // lo plane = chunk ^ 4
    }
    int raddr[2][2];
    #pragma unroll
    for (int pl = 0; pl < 2; ++pl)
        #pragma unroll
        for (int k2 = 0; k2 < 2; ++k2)
            raddr[pl][k2] = hbase + ol*128 + (((pl*4 + k2*2 + half) ^ (ol & 7)) << 4);

    const int w1a = l*16;                               // + frag*1024 immediate
    const int w2a = 24576 + ((ol & 15) + (half << 4))*16;   // + frag*512 immediate

    const auto ld8 = [&](int byteoff) -> ushort8 {
        return *(const ushort8*)((const char*)sLDS + byteoff);
    };

    // ---------------- tile loop: 4 tiles of 32 pixels (one row segment each) ----------------
    const int gw = blockIdx.x*4 + w;      // 8192 waves
    const int t0 = gw*4;
    const int y  = (t0 >> 3) & 255;
    const int b  =  t0 >> 11;
    const int dyt = (y > 0)   ? -256 : 0;
    const int dyb = (y < 255) ?  256 : 0;
    const float fmt = (y > 0)   ? 1.f : 0.f;
    const float fmb = (y < 255) ? 1.f : 0.f;

    for (int i = 0; i < 4; ++i) {
        const int t  = t0 + i;
        const int x0 = (t & 7) << 5;
        const int x  = x0 + ol;

        const int   dxl = (x > 0)   ? -1 : 0;
        const int   dxr = (x < 255) ?  1 : 0;
        const float fml = (x > 0)   ? 1.f : 0.f;
        const float fmr = (x < 255) ? 1.f : 0.f;
        const float ftl = fml*fmt, ftr = fmr*fmt, fbl = fml*fmb, fbr = fmr*fmb;

        // ---- perception directly into A fragments (lane = pixel ol, channels half*8+ci) ----
        const int pbase = (b*16 + half*8)*65536 + y*256 + x;
        ushort8 ahi[3], alo[3];
        #pragma unroll
        for (int ci = 0; ci < 8; ++ci) {
            int ic = pbase + ci*65536;
            int it = ic + dyt, ib = ic + dyb;
            float v00 = grid[it + dxl]*ftl, v01 = grid[it]*fmt, v02 = grid[it + dxr]*ftr;
            float v10 = grid[ic + dxl]*fml, v11 = grid[ic],     v12 = grid[ic + dxr]*fmr;
            float v20 = grid[ib + dxl]*fbl, v21 = grid[ib]*fmb, v22 = grid[ib + dxr]*fbr;
            float sx = (v02 - v00) + 2.f*(v12 - v10) + (v22 - v20);
            float sy = (v20 - v00) + 2.f*(v21 - v01) + (v22 - v02);
            unsigned short h, lo_;
            bsplit(v11, h, lo_); ahi[0][ci] = h; alo[0][ci] = lo_;
            bsplit(sx,  h, lo_); ahi[1][ci] = h; alo[1][ci] = lo_;
            bsplit(sy,  h, lo_); ahi[2][ci] = h; alo[2][ci] = lo_;
        }

        // ---- fused MLP via MFMA ----
        f32x16 acc2;
        #pragma unroll
        for (int r = 0; r < 16; ++r) acc2[r] = b2v;

        #pragma unroll
        for (int og = 0; og < 4; ++og) {
            f32x16 acc1;
            const float bv = b1v[og];
            #pragma unroll
            for (int r = 0; r < 16; ++r) acc1[r] = bv;

            #pragma unroll
            for (int kk = 0; kk < 3; ++kk) {
                bf16x8 a_h = __builtin_bit_cast(bf16x8, ahi[kk]);
                bf16x8 a_l = __builtin_bit_cast(bf16x8, alo[kk]);
                bf16x8 w_h = __builtin_bit_cast(bf16x8, ld8(w1a + ((og*3 + kk)*2 + 0)*1024));
                bf16x8 w_l = __builtin_bit_cast(bf16x8, ld8(w1a + ((og*3 + kk)*2 + 1)*1024));
                acc1 = MFMA(a_h, w_h, acc1);
                acc1 = MFMA(a_h, w_l, acc1);
                acc1 = MFMA(a_l, w_h, acc1);
            }

            // relu + hi/lo split + write H og-slice (wave-private LDS, swizzled)
            #pragma unroll
            for (int r = 0; r < 16; ++r) {
                float hv = fmaxf(acc1[r], 0.f);
                unsigned short hh, hl;
                bsplit(hv, hh, hl);
                const int q = r & 3, imm = (r >> 2) << 10;
                *(unsigned short*)((char*)sLDS + waddrH[q] + imm) = hh;
                *(unsigned short*)((char*)sLDS + waddrL[q] + imm) = hl;
            }

            // GEMM2 partial accumulation over this og's 32 hidden channels
            #pragma unroll
            for (int k2 = 0; k2 < 2; ++k2) {
                ushort8 a2h = ld8(raddr[0][k2]);
                ushort8 a2l = ld8(raddr[1][k2]);
                const int g = (og*2 + k2)*2;
                ushort8 w2h = ld8(w2a + (g + 0)*512);
                ushort8 w2l = ld8(w2a + (g + 1)*512);
                if (!v16) { w2h = (ushort8)0; w2l = (ushort8)0; }   // cols 16..31 are padding
                bf16x8 A2h = __builtin_bit_cast(bf16x8, a2h);
                bf16x8 A2l = __builtin_bit_cast(bf16x8, a2l);
                acc2 = MFMA(A2h, __builtin_bit_cast(bf16x8, w2h), acc2);
                acc2 = MFMA(A2h, __builtin_bit_cast(bf16x8, w2l), acc2);
                acc2 = MFMA(A2l, __builtin_bit_cast(bf16x8, w2h), acc2);
            }
        }

        // ---- store: lane ol = out-channel, 16 pixels, packed as 4x float4 ----
        if (v16) {
            const int ob = (b*16 + ol)*65536 + y*256 + x0 + half*4;
            #pragma unroll
            for (int c = 0; c < 4; ++c) {
                f32x4 v = { acc2[4*c+0], acc2[4*c+1], acc2[4*c+2], acc2[4*c+3] };
                *(f32x4*)&out[ob + c*8] = v;
            }
        }
    }
}

extern "C" void kernel_launch(void* const* d_in, const int* in_sizes, int n_in,
                              void* d_out, int out_size, void* d_ws, size_t ws_size,
                              hipStream_t stream) {
    const float* grid = (const float*)d_in[0];
    const float* W1   = (const float*)d_in[1];
    const float* b1   = (const float*)d_in[2];
    const float* W2   = (const float*)d_in[3];
    const float* b2   = (const float*)d_in[4];
    float* out = (float*)d_out;

    // 2048 blocks x 256 threads = 8192 waves; each wave: 4 tiles of 32 pixels
    nca_mfma_kernel<<<2048, 256, 0, stream>>>(grid, W1, b1, W2, b2, out);
}

// Round 3
// 191.368 us; speedup vs baseline: 1.5621x; 1.2319x over previous
//
#include <hip/hip_runtime.h>

typedef float           f32x16  __attribute__((ext_vector_type(16)));
typedef float           f32x4   __attribute__((ext_vector_type(4)));
typedef __bf16          bf16x8  __attribute__((ext_vector_type(8)));
typedef unsigned short  ushort8 __attribute__((ext_vector_type(8)));
typedef unsigned int    uint4v  __attribute__((ext_vector_type(4)));

#define MFMA(a,b,c) __builtin_amdgcn_mfma_f32_32x32x16_bf16(a, b, c, 0, 0, 0)

__device__ __forceinline__ unsigned fbits(float x) { return __builtin_bit_cast(unsigned, x); }
__device__ __forceinline__ float bitsf(unsigned u) { return __builtin_bit_cast(float, u); }

// split fp32 -> bf16 hi + bf16 lo (truncation; identical numerics to R2)
__device__ __forceinline__ void bsplit(float x, unsigned short& hi, unsigned short& lo) {
    unsigned u = fbits(x);
    hi = (unsigned short)(u >> 16);
    float rem = x - bitsf(u & 0xFFFF0000u);
    lo = (unsigned short)(fbits(rem) >> 16);
}

// LDS (ushort indices):
//   W1 frags: [(og*3+kk)*2+pl]*512 + lane*8          (24576 B)
//   W2 frags: 12288 + [kk2*2+pl]*256 + cidx*8        ( 8192 B)
//   b1 float: ushort idx 16384.. (128 floats, 512 B) -> total 33280 B, 4 blocks/CU
__global__ __launch_bounds__(256, 4) void nca_mfma3_kernel(
    const float* __restrict__ grid,
    const float* __restrict__ W1, const float* __restrict__ b1,
    const float* __restrict__ W2, const float* __restrict__ b2,
    float* __restrict__ out)
{
    __shared__ unsigned short sLDS[16640];
    float* sB1f = (float*)&sLDS[16384];

    const int tid  = threadIdx.x;
    const int l    = tid & 63;
    const int w    = tid >> 6;
    const int half = l >> 5;
    const int ol   = l & 31;

    // ---------------- stage W1 fragments (pre-split, lane-major; sobel /8 folded) ----------------
    #pragma unroll
    for (int i = 0; i < 3; ++i) {
        int sidx = tid + 256*i;          // 0..767
        int ls   = sidx & 63;
        int fp   = sidx >> 6;            // 0..11 = og*3+kk
        int kk   = fp % 3;
        int o    = (fp/3)*32 + (ls & 31);
        int k0   = kk*16 + (ls>>5)*8;
        float sc = (kk == 0) ? 1.0f : 0.125f;
        ushort8 hi8, lo8;
        #pragma unroll
        for (int j = 0; j < 8; ++j) {
            float v = W1[o*48 + k0 + j] * sc;
            unsigned short h, lo_;
            bsplit(v, h, lo_);
            hi8[j] = h; lo8[j] = lo_;
        }
        *(ushort8*)&sLDS[(fp*2 + 0)*512 + ls*8] = hi8;
        *(ushort8*)&sLDS[(fp*2 + 1)*512 + ls*8] = lo8;
    }

    // ---------------- stage W2 fragments ----------------
    {
        int kk2  = tid >> 5;             // 0..7
        int cidx = tid & 31;
        int o    = cidx & 15;
        int hs   = cidx >> 4;
        int k0   = kk2*16 + hs*8;
        ushort8 hi8, lo8;
        #pragma unroll
        for (int j = 0; j < 8; ++j) {
            float v = W2[o*128 + k0 + j];
            unsigned short h, lo_;
            bsplit(v, h, lo_);
            hi8[j] = h; lo8[j] = lo_;
        }
        *(ushort8*)&sLDS[12288 + (kk2*2 + 0)*256 + cidx*8] = hi8;
        *(ushort8*)&sLDS[12288 + (kk2*2 + 1)*256 + cidx*8] = lo8;
    }

    if (tid < 128) sB1f[tid] = b1[tid];

    const bool  v16 = (ol < 16);
    const float b2v = v16 ? b2[ol] : 0.0f;

    __syncthreads();

    const int w1a = l*16;                                  // + frag*1024 byte imm
    const int w2a = 24576 + ((ol & 15) + (half << 4))*16;  // + frag*512 byte imm
    const int b1a = 4*half;                                // float-index base

    const auto ld8 = [&](int byteoff) -> ushort8 {
        return *(const ushort8*)((const char*)sLDS + byteoff);
    };

    // ---------------- XCD-chunked swizzle: each XCD gets 256 contiguous blocks ----------------
    const int bid  = blockIdx.x;
    const int wgid = ((bid & 7) << 8) | (bid >> 3);

    const int gw = wgid*4 + w;            // 8192 waves
    const int t0 = gw*4;
    const int y  = (t0 >> 3) & 255;
    const int b  =  t0 >> 11;
    const int dyt = (y > 0)   ? -256 : 0;
    const int dyb = (y < 255) ?  256 : 0;
    const float fmt = (y > 0)   ? 1.f : 0.f;
    const float fmb = (y < 255) ? 1.f : 0.f;

    for (int i = 0; i < 4; ++i) {
        const int t  = t0 + i;
        const int x0 = (t & 7) << 5;
        const int x  = x0 + ol;

        const int   dxl = (x > 0)   ? -1 : 0;
        const int   dxr = (x < 255) ?  1 : 0;
        const float fml = (x > 0)   ? 1.f : 0.f;
        const float fmr = (x < 255) ? 1.f : 0.f;
        const float ftl = fml*fmt, ftr = fmr*fmt, fbl = fml*fmb, fbr = fmr*fmb;

        // opaque copies of LDS bases: defeat LICM/CSE of weight loads across tiles
        int w1ai = w1a, w2ai = w2a, b1ai = b1a;
        asm volatile("" : "+v"(w1ai), "+v"(w2ai), "+v"(b1ai));

        // ---- perception into B-fragments (lane = pixel col, k = half*8+ci) ----
        const int pbase = (b*16 + half*8)*65536 + y*256 + x;
        ushort8 ahi[3], alo[3];
        #pragma unroll
        for (int ci = 0; ci < 8; ++ci) {
            int ic = pbase + ci*65536;
            int it = ic + dyt, ib = ic + dyb;
            float v00 = grid[it + dxl]*ftl, v01 = grid[it]*fmt, v02 = grid[it + dxr]*ftr;
            float v10 = grid[ic + dxl]*fml, v11 = grid[ic],     v12 = grid[ic + dxr]*fmr;
            float v20 = grid[ib + dxl]*fbl, v21 = grid[ib]*fmb, v22 = grid[ib + dxr]*fbr;
            float sx = (v02 - v00) + 2.f*(v12 - v10) + (v22 - v20);
            float sy = (v20 - v00) + 2.f*(v21 - v01) + (v22 - v02);
            unsigned short h, lo_;
            bsplit(v11, h, lo_); ahi[0][ci] = h; alo[0][ci] = lo_;
            bsplit(sx,  h, lo_); ahi[1][ci] = h; alo[1][ci] = lo_;
            bsplit(sy,  h, lo_); ahi[2][ci] = h; alo[2][ci] = lo_;
        }

        f32x16 acc2;
        #pragma unroll
        for (int r = 0; r < 16; ++r) acc2[r] = b2v;

        #pragma unroll
        for (int og = 0; og < 4; ++og) {
            // acc1 init = b1 (pixel-major D layout: reg r <-> o' = (r&3) + 8*(r>>2) + 4*half)
            f32x16 acc1;
            #pragma unroll
            for (int T = 0; T < 4; ++T) {
                f32x4 q = *(const f32x4*)&sB1f[b1ai + og*32 + 8*T];
                acc1[4*T+0] = q[0]; acc1[4*T+1] = q[1];
                acc1[4*T+2] = q[2]; acc1[4*T+3] = q[3];
            }

            // GEMM1: D = W1 x P  (A = W1 frag lane=o-row, B = perception lane=pixel-col)
            #pragma unroll
            for (int kk = 0; kk < 3; ++kk) {
                bf16x8 ph  = __builtin_bit_cast(bf16x8, ahi[kk]);
                bf16x8 pl  = __builtin_bit_cast(bf16x8, alo[kk]);
                bf16x8 w_h = __builtin_bit_cast(bf16x8, ld8(w1ai + ((og*3 + kk)*2 + 0)*1024));
                bf16x8 w_l = __builtin_bit_cast(bf16x8, ld8(w1ai + ((og*3 + kk)*2 + 1)*1024));
                acc1 = MFMA(w_h, ph, acc1);
                acc1 = MFMA(w_h, pl, acc1);
                acc1 = MFMA(w_l, ph, acc1);
            }

            // relu + hi/lo split + pack pairs (dword d holds elems 2d,2d+1)
            unsigned Phi[8], Plo[8];
            #pragma unroll
            for (int T = 0; T < 4; ++T) {
                float h0 = fmaxf(acc1[4*T+0], 0.f), h1 = fmaxf(acc1[4*T+1], 0.f);
                float h2 = fmaxf(acc1[4*T+2], 0.f), h3 = fmaxf(acc1[4*T+3], 0.f);
                unsigned u0 = fbits(h0), u1 = fbits(h1), u2 = fbits(h2), u3 = fbits(h3);
                Phi[2*T+0] = (u0 >> 16) | (u1 & 0xFFFF0000u);
                Phi[2*T+1] = (u2 >> 16) | (u3 & 0xFFFF0000u);
                float r0 = h0 - bitsf(u0 & 0xFFFF0000u);
                float r1 = h1 - bitsf(u1 & 0xFFFF0000u);
                float r2 = h2 - bitsf(u2 & 0xFFFF0000u);
                float r3 = h3 - bitsf(u3 & 0xFFFF0000u);
                Plo[2*T+0] = (fbits(r0) >> 16) | (fbits(r1) & 0xFFFF0000u);
                Plo[2*T+1] = (fbits(r2) >> 16) | (fbits(r3) & 0xFFFF0000u);
            }

            // half-swap -> GEMM2 A-fragments (lane = pixel row, k = hidden)
            #pragma unroll
            for (int c = 0; c < 2; ++c) {
                unsigned fa0 = Phi[(2*c)*2+0], fb0 = Phi[(2*c+1)*2+0];
                unsigned fa1 = Phi[(2*c)*2+1], fb1 = Phi[(2*c+1)*2+1];
                asm volatile("v_permlane32_swap_b32 %0, %1" : "+v"(fa0), "+v"(fb0));
                asm volatile("v_permlane32_swap_b32 %0, %1" : "+v"(fa1), "+v"(fb1));
                unsigned la0 = Plo[(2*c)*2+0], lb0 = Plo[(2*c+1)*2+0];
                unsigned la1 = Plo[(2*c)*2+1], lb1 = Plo[(2*c+1)*2+1];
                asm volatile("v_permlane32_swap_b32 %0, %1" : "+v"(la0), "+v"(lb0));
                asm volatile("v_permlane32_swap_b32 %0, %1" : "+v"(la1), "+v"(lb1));
                uint4v hv_ = { fa0, fa1, fb0, fb1 };
                uint4v lv_ = { la0, la1, lb0, lb1 };
                bf16x8 A2h = __builtin_bit_cast(bf16x8, hv_);
                bf16x8 A2l = __builtin_bit_cast(bf16x8, lv_);

                const int g = (og*2 + c)*2;
                bf16x8 w2h = __builtin_bit_cast(bf16x8, ld8(w2ai + (g + 0)*512));
                bf16x8 w2l = __builtin_bit_cast(bf16x8, ld8(w2ai + (g + 1)*512));
                acc2 = MFMA(A2h, w2h, acc2);
                acc2 = MFMA(A2h, w2l, acc2);
                acc2 = MFMA(A2l, w2h, acc2);
            }
        }

        // ---- store: lane ol(<16) = out-channel; regs = 16 pixels as 4x float4 ----
        if (v16) {
            const int ob = (b*16 + ol)*65536 + y*256 + x0 + half*4;
            #pragma unroll
            for (int c = 0; c < 4; ++c) {
                f32x4 v = { acc2[4*c+0], acc2[4*c+1], acc2[4*c+2], acc2[4*c+3] };
                *(f32x4*)&out[ob + c*8] = v;
            }
        }
    }
}

extern "C" void kernel_launch(void* const* d_in, const int* in_sizes, int n_in,
                              void* d_out, int out_size, void* d_ws, size_t ws_size,
                              hipStream_t stream) {
    const float* grid = (const float*)d_in[0];
    const float* W1   = (const float*)d_in[1];
    const float* b1   = (const float*)d_in[2];
    const float* W2   = (const float*)d_in[3];
    const float* b2   = (const float*)d_in[4];
    float* out = (float*)d_out;

    nca_mfma3_kernel<<<2048, 256, 0, stream>>>(grid, W1, b1, W2, b2, out);
}